// Round 3
// baseline (1136.071 us; speedup 1.0000x reference)
//
#include <hip/hip_runtime.h>
#include <math.h>
#include <stdint.h>

typedef unsigned short u16;
typedef __attribute__((ext_vector_type(8))) short bf8;      // 8 bf16 MFMA operand (4 VGPR)
typedef __attribute__((ext_vector_type(8))) unsigned short us8;
typedef __attribute__((ext_vector_type(4))) float f4;

#define B_  32
#define T_  577
#define D_  768
#define BT  18464
#define H3  2304
#define HD  3072
#define NH  12
#define DH  64
#define TT  332929ull        // T_*T_
#define TP  608              // T_ padded to mult of 32 (K dim of AV)
#define LNEPS 1e-6f

// async global->LDS, 16B per lane; dest = wave-uniform base + lane*16
#define GLOAD_LDS16(gp, lp)                                                \
  __builtin_amdgcn_global_load_lds(                                       \
      (const __attribute__((address_space(1))) void*)(gp),                 \
      (__attribute__((address_space(3))) void*)(unsigned)(uintptr_t)(lp),  \
      16, 0, 0)

__device__ __forceinline__ u16 f2bf(float f) {
  unsigned int u = __float_as_uint(f);
  u += 0x7fffu + ((u >> 16) & 1u);       // round-to-nearest-even
  return (u16)(u >> 16);
}

// fast erf (Abramowitz-Stegun 7.1.26, max abs err 1.5e-7 << bf16 ulp)
__device__ __forceinline__ float gelu_fast(float v) {
  float ax = fabsf(v) * 0.70710678118654752f;
  float t  = __builtin_amdgcn_rcpf(fmaf(0.3275911f, ax, 1.0f));
  float p  = fmaf(fmaf(fmaf(fmaf(1.061405429f, t, -1.453152027f), t,
                            1.421413741f), t, -0.284496736f), t, 0.254829592f);
  float er = 1.0f - p * t * __expf(-ax * ax);
  er = v < 0.0f ? -er : er;
  return 0.5f * v * (1.0f + er);
}

// ---------------- LayerNorm fp32 -> bf16 ----------------
__global__ __launch_bounds__(256) void ln_bf16(const float* __restrict__ x,
    const float* __restrict__ w, const float* __restrict__ b, u16* __restrict__ y) {
  int row = blockIdx.x;
  const float* xr = x + (size_t)row * D_;
  int t = threadIdx.x;
  float v0 = xr[t], v1 = xr[t + 256], v2 = xr[t + 512];
  float s  = v0 + v1 + v2;
  float ss = v0*v0 + v1*v1 + v2*v2;
  #pragma unroll
  for (int o = 32; o >= 1; o >>= 1) {
    s  += __shfl_xor(s,  o, 64);
    ss += __shfl_xor(ss, o, 64);
  }
  __shared__ float rs_[4], rss_[4];
  int wid = t >> 6;
  if ((t & 63) == 0) { rs_[wid] = s; rss_[wid] = ss; }
  __syncthreads();
  s  = rs_[0]  + rs_[1]  + rs_[2]  + rs_[3];
  ss = rss_[0] + rss_[1] + rss_[2] + rss_[3];
  float mu  = s * (1.0f / D_);
  float var = ss * (1.0f / D_) - mu * mu;
  float rstd = rsqrtf(var + LNEPS);
  u16* yr = y + (size_t)row * D_;
  yr[t]       = f2bf((v0 - mu) * rstd * w[t]       + b[t]);
  yr[t + 256] = f2bf((v1 - mu) * rstd * w[t + 256] + b[t + 256]);
  yr[t + 512] = f2bf((v2 - mu) * rstd * w[t + 512] + b[t + 512]);
}

// ---------------- weight fp32 [K,N] -> bf16 transposed [N,K] ----------------
__global__ __launch_bounds__(256) void wconv(const float* __restrict__ W,
    u16* __restrict__ Wt, int K, int N) {
  __shared__ float tile[64][68];
  int n0 = blockIdx.x * 64, k0 = blockIdx.y * 64;
  int t = threadIdx.x;
  #pragma unroll
  for (int r = 0; r < 4; ++r) {
    int flat = r * 256 + t;
    int kr = flat >> 4, g = flat & 15;
    float4 v = *(const float4*)(W + (size_t)(k0 + kr) * N + n0 + g * 4);
    *(float4*)&tile[kr][g * 4] = v;
  }
  __syncthreads();
  #pragma unroll
  for (int r = 0; r < 2; ++r) {
    int flat = r * 256 + t;
    int n = flat >> 3, g2 = flat & 7;
    us8 o;
    #pragma unroll
    for (int j = 0; j < 8; ++j) o[j] = f2bf(tile[g2 * 8 + j][n]);
    *(us8*)(Wt + (size_t)(n0 + n) * K + k0 + g2 * 8) = o;
  }
}

// ---------------- build Vt [z][128][TP] from qkvbf V-slot ----------------
__global__ __launch_bounds__(256) void vt_prep(const u16* __restrict__ qkvbf,
    u16* __restrict__ Vt) {
  int z = blockIdx.z;
  int bb = z / NH, h = z - bb * NH;
  u16* out = Vt + (size_t)z * 128 * TP;
  int k0 = blockIdx.x * 64;
  int t = threadIdx.x;
  if (blockIdx.y == 1) {
    #pragma unroll
    for (int r = 0; r < 2; ++r) {
      int flat = r * 256 + t;
      int n = 64 + (flat >> 3), g = flat & 7;
      int kc = k0 + g * 8;
      if (kc < TP) {
        us8 zz = {0,0,0,0,0,0,0,0};
        *(us8*)(out + (size_t)n * TP + kc) = zz;
      }
    }
    return;
  }
  __shared__ u16 tile[64][72];
  const u16* src = qkvbf + ((size_t)bb * T_) * H3 + 2 * D_ + h * DH;
  #pragma unroll
  for (int r = 0; r < 2; ++r) {
    int flat = r * 256 + t;
    int kr = flat >> 3, g = flat & 7;
    int gk = k0 + kr;
    us8 v = {0,0,0,0,0,0,0,0};
    if (gk < T_) v = *(const us8*)(src + (size_t)gk * H3 + g * 8);
    *(us8*)&tile[kr][g * 8] = v;
  }
  __syncthreads();
  #pragma unroll
  for (int r = 0; r < 2; ++r) {
    int flat = r * 256 + t;
    int n = flat >> 3, g2 = flat & 7;
    int kc = k0 + g2 * 8;
    if (kc < TP) {
      us8 o;
      #pragma unroll
      for (int j = 0; j < 8; ++j) o[j] = tile[g2 * 8 + j][n];
      *(us8*)(out + (size_t)n * TP + kc) = o;
    }
  }
}

// ---------------- softmax over heads; fp32 dp -> bf16 P (padded to TP) ----------------
__global__ __launch_bounds__(256) void softmax_pad(const float* __restrict__ dp,
    u16* __restrict__ P) {
  int bb = blockIdx.y;
  int i = blockIdx.x * 256 + threadIdx.x;
  if (i >= T_ * TP) return;
  int qq = i / TP, kp = i - qq * TP;
  u16* Pb = P + (size_t)bb * NH * T_ * TP + (size_t)qq * TP + kp;
  if (kp >= T_) {
    #pragma unroll
    for (int h = 0; h < NH; ++h) Pb[(size_t)h * T_ * TP] = 0;
    return;
  }
  const float* db = dp + (size_t)bb * NH * TT + (size_t)qq * T_ + kp;
  float v[NH];
  float m = -1e30f;
  #pragma unroll
  for (int h = 0; h < NH; ++h) { v[h] = db[(size_t)h * TT]; m = fmaxf(m, v[h]); }
  float s = 0.f;
  #pragma unroll
  for (int h = 0; h < NH; ++h) { v[h] = expf(v[h] - m); s += v[h]; }
  float inv = 1.0f / s;
  #pragma unroll
  for (int h = 0; h < NH; ++h) Pb[(size_t)h * T_ * TP] = f2bf(v[h] * inv);
}

// ---------------- bf16 MFMA GEMM: 128x128 tile (attention GEMMs) ----------------
// EPI: 3 = *scale -> f32 C      4 = plain -> bf16 C
template <int EPI>
__global__ __launch_bounds__(256) void gemm_bf16(
    const u16* __restrict__ Abase, int lda,
    const u16* __restrict__ Bbase, int ldb,
    const float* __restrict__ bias,
    const float* __restrict__ res, int ldr,
    float* __restrict__ Cf, u16* __restrict__ Cb, int ldc,
    int M, int Nst, int Nb, int K, float scale, int bmode) {
  __shared__ u16 As[128 * 32];
  __shared__ u16 Bs[128 * 32];
  int z = blockIdx.z;
  size_t aoff = 0, boff = 0, coff = 0;
  if (bmode == 1) {
    int bb = z / NH, h = z - bb * NH;
    aoff = (size_t)bb * T_ * H3 + (size_t)h * DH;
    boff = aoff + D_;
    coff = (size_t)z * TT;
  } else if (bmode == 2) {
    int bb = z / NH, h = z - bb * NH;
    aoff = (size_t)z * T_ * TP;
    boff = (size_t)z * 128 * TP;
    coff = (size_t)bb * T_ * H3 + (size_t)h * DH;
  }
  const u16* A  = Abase + aoff;
  const u16* Bt = Bbase + boff;

  int bx = blockIdx.x, by = blockIdx.y;
  int m_base = by * 128, n_base = bx * 128;

  int tid = threadIdx.x;
  int wid = tid >> 6, lane = tid & 63;
  int wm = (wid >> 1) * 64, wn = (wid & 1) * 64;
  int lm = lane & 15, q = lane >> 4;
  int srow = tid >> 2, sg = tid & 3;

  int gm0 = m_base + srow;       gm0 = gm0 < M ? gm0 : M - 1;
  int gm1 = m_base + 64 + srow;  gm1 = gm1 < M ? gm1 : M - 1;
  int gn0 = n_base + srow;       gn0 = gn0 < Nb ? gn0 : Nb - 1;
  int gn1 = n_base + 64 + srow;  gn1 = gn1 < Nb ? gn1 : Nb - 1;
  const u16* a0 = A  + (size_t)gm0 * lda + sg * 8;
  const u16* a1 = A  + (size_t)gm1 * lda + sg * 8;
  const u16* b0 = Bt + (size_t)gn0 * ldb + sg * 8;
  const u16* b1 = Bt + (size_t)gn1 * ldb + sg * 8;
  u16* lA = As + wid * 512;   // wave-uniform base; lane dest = +lane*16B
  u16* lB = Bs + wid * 512;

  f4 acc[4][4] = {};

  for (int kc = 0; kc < K; kc += 32) {
    GLOAD_LDS16(a0 + kc, lA);
    GLOAD_LDS16(a1 + kc, lA + 2048);
    GLOAD_LDS16(b0 + kc, lB);
    GLOAD_LDS16(b1 + kc, lB + 2048);
    __syncthreads();
    bf8 af[4], bfr[4];
    #pragma unroll
    for (int mt = 0; mt < 4; ++mt)
      af[mt] = *(const bf8*)&As[(wm + mt * 16 + lm) * 32 + q * 8];
    #pragma unroll
    for (int nt = 0; nt < 4; ++nt)
      bfr[nt] = *(const bf8*)&Bs[(wn + nt * 16 + lm) * 32 + q * 8];
    #pragma unroll
    for (int mt = 0; mt < 4; ++mt)
      #pragma unroll
      for (int nt = 0; nt < 4; ++nt)
        acc[mt][nt] = __builtin_amdgcn_mfma_f32_16x16x32_bf16(af[mt], bfr[nt], acc[mt][nt], 0, 0, 0);
    __syncthreads();
  }

  // epilogue: C/D layout col = lane&15, row = quad*4 + reg
  #pragma unroll
  for (int mt = 0; mt < 4; ++mt) {
    #pragma unroll
    for (int i = 0; i < 4; ++i) {
      int grow = m_base + wm + mt * 16 + q * 4 + i;
      if (grow >= M) continue;
      #pragma unroll
      for (int nt = 0; nt < 4; ++nt) {
        int gcol = n_base + wn + nt * 16 + lm;
        if (gcol >= Nst) continue;
        float v = acc[mt][nt][i];
        if (EPI == 3) {
          Cf[coff + (size_t)grow * ldc + gcol] = v * scale;
        } else {
          Cb[coff + (size_t)grow * ldc + gcol] = f2bf(v);
        }
      }
    }
  }
}

// ============ 128x128 BK=32 double-buffered pipelined GEMM ============
// 4 waves (2x2), per-wave 64x64 (acc[4][4]); LDS 32 KiB -> 4 blocks/CU so
// independent blocks overlap barrier/LDS-drain/epilogue stalls (round-2
// post-mortem: at 2 blocks/CU everything idled at <40% of its roofline).
// Granule XOR-swizzle for 4-granule (64 B) rows: slot s of row r holds
// granule s^((r>>1)&3) -> each 16-lane read group covers all 32 banks at
// 2-way (free). Staged via inverse-swizzled GLOBAL source (rule #21).
// Counted vmcnt(4): tile t+1's 4 loads stay in flight across barriers.
// EPI: 0 = bias -> bf16   1 = bias+res -> f32   2 = bias+gelu -> bf16
template <int EPI>
__global__ __launch_bounds__(256, 4) void gemm128(
    const u16* __restrict__ A, int lda,
    const u16* __restrict__ Bt, int ldb,
    const float* __restrict__ bias,
    const float* __restrict__ res, int ldr,
    float* __restrict__ Cf, u16* __restrict__ Cb, int ldc,
    int M, int K) {
  __shared__ u16 lds[16384];           // A: [2][4096] @0, B: [2][4096] @8192
  const int NKT = K >> 5;

  // bijective XCD swizzle (m204)
  int gx = gridDim.x;
  int nwg = gx * (int)gridDim.y;
  int orig = blockIdx.y * gx + blockIdx.x;
  int qq = nwg >> 3, rr = nwg & 7;
  int xcd = orig & 7, loc = orig >> 3;
  int wg = (xcd < rr ? xcd * (qq + 1) : rr * (qq + 1) + (xcd - rr) * qq) + loc;
  int by = wg / gx, bx = wg - by * gx;
  int m_base = by * 128, n_base = bx * 128;

  int tid = threadIdx.x;
  int wid = tid >> 6, lane = tid & 63;
  int wr = wid >> 1, wc = wid & 1;
  int lm = lane & 15, q = lane >> 4;

  // staging: thread -> row r0 (64 rows/piece), slot tid&3 holds granule
  // g0 = (tid&3) ^ ((r0>>1)&3)
  int r0 = tid >> 2, g0 = (tid & 3) ^ ((r0 >> 1) & 3);
  int M1 = M - 1;
  int ra0 = m_base + r0;       ra0 = ra0 < M1 ? ra0 : M1;
  int ra1 = m_base + 64 + r0;  ra1 = ra1 < M1 ? ra1 : M1;
  const u16* pa0 = A + (size_t)ra0 * lda + g0 * 8;
  const u16* pa1 = A + (size_t)ra1 * lda + g0 * 8;
  const u16* pb0 = Bt + (size_t)(n_base + r0)      * ldb + g0 * 8;
  const u16* pb1 = Bt + (size_t)(n_base + 64 + r0) * ldb + g0 * 8;

  auto STAGE = [&](int p, int t) {
    size_t ko = (size_t)t * 32;
    int Ab = p * 4096, Bb = 8192 + p * 4096;
    GLOAD_LDS16(pa0 + ko, lds + Ab + tid * 8);
    GLOAD_LDS16(pa1 + ko, lds + Ab + 2048 + tid * 8);
    GLOAD_LDS16(pb0 + ko, lds + Bb + tid * 8);
    GLOAD_LDS16(pb1 + ko, lds + Bb + 2048 + tid * 8);
  };

  // ds_read: logical granule q of row lm is at slot q^((lm>>1)&3)
  int ge0 = (q ^ ((lm >> 1) & 3)) * 8;
  int aoffb = (wr * 64 + lm) * 32;
  int boffb = 8192 + (wc * 64 + lm) * 32;

  f4 acc[4][4] = {};

  STAGE(0, 0);                         // prologue: tile 0 -> buf 0

  for (int t = 0; t < NKT; ++t) {
    int p = t & 1;
    int tN = t + 1 < NKT ? t + 1 : t;

    STAGE(p ^ 1, tN);                            // tile t+1 -> other bufs
    asm volatile("s_waitcnt vmcnt(4)" ::: "memory");  // tile t landed (mine)
    __builtin_amdgcn_s_barrier();                // tile t landed (all waves)
    __builtin_amdgcn_sched_barrier(0);

    bf8 af[4], bfr[4];
    #pragma unroll
    for (int mt = 0; mt < 4; ++mt)
      af[mt] = *(const bf8*)(lds + p * 4096 + aoffb + mt * 512 + ge0);
    #pragma unroll
    for (int nt = 0; nt < 4; ++nt)
      bfr[nt] = *(const bf8*)(lds + p * 4096 + boffb + nt * 512 + ge0);
    asm volatile("s_waitcnt lgkmcnt(0)" ::: "memory");
    __builtin_amdgcn_sched_barrier(0);

    __builtin_amdgcn_s_setprio(1);
    #pragma unroll
    for (int mt = 0; mt < 4; ++mt)
      #pragma unroll
      for (int nt = 0; nt < 4; ++nt)
        acc[mt][nt] = __builtin_amdgcn_mfma_f32_16x16x32_bf16(
            af[mt], bfr[nt], acc[mt][nt], 0, 0, 0);
    __builtin_amdgcn_s_setprio(0);

    __builtin_amdgcn_s_barrier();                // reads done before overwrite
    __builtin_amdgcn_sched_barrier(0);
  }

  asm volatile("s_waitcnt vmcnt(0)" ::: "memory");   // drain dummy restage

  // epilogue: C/D layout col = lane&15, row = quad*4 + reg
  #pragma unroll
  for (int mt = 0; mt < 4; ++mt) {
    #pragma unroll
    for (int i = 0; i < 4; ++i) {
      int grow = m_base + wr * 64 + mt * 16 + q * 4 + i;
      if (grow >= M) continue;
      #pragma unroll
      for (int nt = 0; nt < 4; ++nt) {
        int gcol = n_base + wc * 64 + nt * 16 + lm;
        float v = acc[mt][nt][i];
        if (EPI == 0) {
          v += bias[gcol];
          Cb[(size_t)grow * ldc + gcol] = f2bf(v);
        } else if (EPI == 1) {
          v += bias[gcol] + res[(size_t)grow * ldr + gcol];
          Cf[(size_t)grow * ldc + gcol] = v;
        } else {
          v += bias[gcol];
          Cb[(size_t)grow * ldc + gcol] = f2bf(gelu_fast(v));
        }
      }
    }
  }
}

// ---------------- launch ----------------
extern "C" void kernel_launch(void* const* d_in, const int* in_sizes, int n_in,
                              void* d_out, int out_size, void* d_ws, size_t ws_size,
                              hipStream_t stream) {
  const float* x     = (const float*)d_in[0];
  const float* ln1w  = (const float*)d_in[1];
  const float* ln1b  = (const float*)d_in[2];
  const float* qkvw  = (const float*)d_in[3];
  const float* qkvb  = (const float*)d_in[4];
  const float* projw = (const float*)d_in[5];
  const float* projb = (const float*)d_in[6];
  const float* ln2w  = (const float*)d_in[7];
  const float* ln2b  = (const float*)d_in[8];
  const float* fc1w  = (const float*)d_in[9];
  const float* fc1b  = (const float*)d_in[10];
  const float* fc2w  = (const float*)d_in[11];
  const float* fc2b  = (const float*)d_in[12];
  float* out = (float*)d_out;

  // ---- workspace layout ----
  u16* qkvwT  = (u16*)d_ws;                       // [2304][768]
  u16* projwT = qkvwT  + (size_t)H3 * D_;         // [768][768]
  u16* fc1wT  = projwT + (size_t)D_ * D_;         // [3072][768]
  u16* fc2wT  = fc1wT  + (size_t)HD * D_;         // [768][3072]
  char* chunk = (char*)(fc2wT + (size_t)D_ * HD);
  const size_t wbytes = ((size_t)H3 * D_ + (size_t)D_ * D_ + 2 * (size_t)HD * D_) * 2;
  size_t avail = ws_size - wbytes;

  const size_t per_batch =
      (size_t)T_ * D_ * 2 + (size_t)T_ * H3 * 2 + (size_t)NH * TT * 4 +
      (size_t)NH * T_ * TP * 2 + (size_t)NH * 128 * TP * 2;
  int NB = (int)(avail / per_batch);
  if (NB < 1)  NB = 1;
  if (NB > B_) NB = B_;

  u16*   ybf   = (u16*)chunk;
  u16*   qkvbf = ybf + (size_t)NB * T_ * D_;
  float* dp    = (float*)(qkvbf + (size_t)NB * T_ * H3);
  u16*   P     = (u16*)(dp + (size_t)NB * NH * TT);
  u16*   Vt    = P + (size_t)NB * NH * T_ * TP;

  // ---- weights: fp32 [K,N] -> bf16 [N,K] ----
  wconv<<<dim3(H3 / 64, D_ / 64), 256, 0, stream>>>(qkvw, qkvwT, D_, H3);
  wconv<<<dim3(D_ / 64, D_ / 64), 256, 0, stream>>>(projw, projwT, D_, D_);
  wconv<<<dim3(HD / 64, D_ / 64), 256, 0, stream>>>(fc1w, fc1wT, D_, HD);
  wconv<<<dim3(D_ / 64, HD / 64), 256, 0, stream>>>(fc2w, fc2wT, HD, D_);

  // ---- attention branch, chunked over batches ----
  for (int b0 = 0; b0 < B_; b0 += NB) {
    int nb = (B_ - b0 < NB) ? (B_ - b0) : NB;
    int rows = nb * T_;
    int mb = (rows + 127) / 128;
    const float* xc = x + (size_t)b0 * T_ * D_;
    float* outc = out + (size_t)b0 * T_ * D_;

    ln_bf16<<<rows, 256, 0, stream>>>(xc, ln1w, ln1b, ybf);
    gemm128<0><<<dim3(H3 / 128, mb), 256, 0, stream>>>(
        ybf, D_, qkvwT, D_, qkvb, nullptr, 0, nullptr, qkvbf, H3,
        rows, D_);
    vt_prep<<<dim3(10, 2, nb * NH), 256, 0, stream>>>(qkvbf, Vt);
    gemm_bf16<3><<<dim3(5, 5, nb * NH), 256, 0, stream>>>(
        qkvbf, H3, qkvbf, H3, nullptr, nullptr, 0, dp, nullptr, T_,
        T_, T_, T_, DH, 0.125f, 1);
    softmax_pad<<<dim3((T_ * TP + 255) / 256, nb), 256, 0, stream>>>(dp, P);
    gemm_bf16<4><<<dim3(1, 5, nb * NH), 256, 0, stream>>>(
        P, TP, Vt, TP, nullptr, nullptr, 0, nullptr, qkvbf, H3,
        T_, DH, 128, TP, 1.f, 2);
    gemm128<1><<<dim3(D_ / 128, mb), 256, 0, stream>>>(
        qkvbf, H3, projwT, D_, projb, xc, D_, outc, nullptr, D_,
        rows, D_);
  }

  // ---- MLP branch, chunked over rows ----
  size_t chrows = avail / ((size_t)D_ * 2 + (size_t)HD * 2);
  int CH = (chrows > (size_t)BT) ? BT : (int)chrows;
  CH &= ~127;
  if (CH < 128) CH = 128;
  for (int r0 = 0; r0 < BT; r0 += CH) {
    int rows = (BT - r0 < CH) ? (BT - r0) : CH;
    int mb = (rows + 127) / 128;
    float* oc = out + (size_t)r0 * D_;
    u16* y2  = (u16*)chunk;
    u16* hdn = y2 + (size_t)CH * D_;

    ln_bf16<<<rows, 256, 0, stream>>>(oc, ln2w, ln2b, y2);
    gemm128<2><<<dim3(HD / 128, mb), 256, 0, stream>>>(
        y2, D_, fc1wT, D_, fc1b, nullptr, 0, nullptr, hdn, HD,
        rows, D_);
    gemm128<1><<<dim3(D_ / 128, mb), 256, 0, stream>>>(
        hdn, HD, fc2wT, HD, fc2b, oc, D_, oc, nullptr, D_,
        rows, HD);
  }
}

// Round 4
// 854.881 us; speedup vs baseline: 1.3289x; 1.3289x over previous
//
#include <hip/hip_runtime.h>
#include <math.h>
#include <stdint.h>

typedef unsigned short u16;
typedef __attribute__((ext_vector_type(8))) short bf8;      // 8 bf16 MFMA operand (4 VGPR)
typedef __attribute__((ext_vector_type(8))) unsigned short us8;
typedef __attribute__((ext_vector_type(4))) float f4;

#define B_  32
#define T_  577
#define D_  768
#define BT  18464
#define H3  2304
#define HD  3072
#define NH  12
#define DH  64
#define TP  608              // T_ padded to mult of 32
#define LNEPS 1e-6f
#define SM_SCALE 0.18033688f // 0.125 * log2(e)

// async global->LDS, 16B per lane; dest = wave-uniform base + lane*16
#define GLOAD_LDS16(gp, lp)                                                \
  __builtin_amdgcn_global_load_lds(                                       \
      (const __attribute__((address_space(1))) void*)(gp),                 \
      (__attribute__((address_space(3))) void*)(unsigned)(uintptr_t)(lp),  \
      16, 0, 0)

__device__ __forceinline__ u16 f2bf(float f) {
  unsigned int u = __float_as_uint(f);
  u += 0x7fffu + ((u >> 16) & 1u);       // round-to-nearest-even
  return (u16)(u >> 16);
}

// fast erf (Abramowitz-Stegun 7.1.26, max abs err 1.5e-7 << bf16 ulp)
__device__ __forceinline__ float gelu_fast(float v) {
  float ax = fabsf(v) * 0.70710678118654752f;
  float t  = __builtin_amdgcn_rcpf(fmaf(0.3275911f, ax, 1.0f));
  float p  = fmaf(fmaf(fmaf(fmaf(1.061405429f, t, -1.453152027f), t,
                            1.421413741f), t, -0.284496736f), t, 0.254829592f);
  float er = 1.0f - p * t * __expf(-ax * ax);
  er = v < 0.0f ? -er : er;
  return 0.5f * v * (1.0f + er);
}

// ---------------- LayerNorm fp32 -> bf16 ----------------
__global__ __launch_bounds__(256) void ln_bf16(const float* __restrict__ x,
    const float* __restrict__ w, const float* __restrict__ b, u16* __restrict__ y) {
  int row = blockIdx.x;
  const float* xr = x + (size_t)row * D_;
  int t = threadIdx.x;
  float v0 = xr[t], v1 = xr[t + 256], v2 = xr[t + 512];
  float s  = v0 + v1 + v2;
  float ss = v0*v0 + v1*v1 + v2*v2;
  #pragma unroll
  for (int o = 32; o >= 1; o >>= 1) {
    s  += __shfl_xor(s,  o, 64);
    ss += __shfl_xor(ss, o, 64);
  }
  __shared__ float rs_[4], rss_[4];
  int wid = t >> 6;
  if ((t & 63) == 0) { rs_[wid] = s; rss_[wid] = ss; }
  __syncthreads();
  s  = rs_[0]  + rs_[1]  + rs_[2]  + rs_[3];
  ss = rss_[0] + rss_[1] + rss_[2] + rss_[3];
  float mu  = s * (1.0f / D_);
  float var = ss * (1.0f / D_) - mu * mu;
  float rstd = rsqrtf(var + LNEPS);
  u16* yr = y + (size_t)row * D_;
  yr[t]       = f2bf((v0 - mu) * rstd * w[t]       + b[t]);
  yr[t + 256] = f2bf((v1 - mu) * rstd * w[t + 256] + b[t + 256]);
  yr[t + 512] = f2bf((v2 - mu) * rstd * w[t + 512] + b[t + 512]);
}

// ---------------- weight fp32 [K,N] -> bf16 transposed [N,K] ----------------
__global__ __launch_bounds__(256) void wconv(const float* __restrict__ W,
    u16* __restrict__ Wt, int K, int N) {
  __shared__ float tile[64][68];
  int n0 = blockIdx.x * 64, k0 = blockIdx.y * 64;
  int t = threadIdx.x;
  #pragma unroll
  for (int r = 0; r < 4; ++r) {
    int flat = r * 256 + t;
    int kr = flat >> 4, g = flat & 15;
    float4 v = *(const float4*)(W + (size_t)(k0 + kr) * N + n0 + g * 4);
    *(float4*)&tile[kr][g * 4] = v;
  }
  __syncthreads();
  #pragma unroll
  for (int r = 0; r < 2; ++r) {
    int flat = r * 256 + t;
    int n = flat >> 3, g2 = flat & 7;
    us8 o;
    #pragma unroll
    for (int j = 0; j < 8; ++j) o[j] = f2bf(tile[g2 * 8 + j][n]);
    *(us8*)(Wt + (size_t)(n0 + n) * K + k0 + g2 * 8) = o;
  }
}

// ---------------- build Vt [z][128][TP] from qkvbf V-slot ----------------
__global__ __launch_bounds__(256) void vt_prep(const u16* __restrict__ qkvbf,
    u16* __restrict__ Vt) {
  int z = blockIdx.z;
  int bb = z / NH, h = z - bb * NH;
  u16* out = Vt + (size_t)z * 128 * TP;
  int k0 = blockIdx.x * 64;
  int t = threadIdx.x;
  __shared__ u16 tile[64][72];
  const u16* src = qkvbf + ((size_t)bb * T_) * H3 + 2 * D_ + h * DH;
  #pragma unroll
  for (int r = 0; r < 2; ++r) {
    int flat = r * 256 + t;
    int kr = flat >> 3, g = flat & 7;
    int gk = k0 + kr;
    us8 v = {0,0,0,0,0,0,0,0};
    if (gk < T_) v = *(const us8*)(src + (size_t)gk * H3 + g * 8);
    *(us8*)&tile[kr][g * 8] = v;
  }
  __syncthreads();
  #pragma unroll
  for (int r = 0; r < 2; ++r) {
    int flat = r * 256 + t;
    int n = flat >> 3, g2 = flat & 7;
    int kc = k0 + g2 * 8;
    if (kc < TP) {
      us8 o;
      #pragma unroll
      for (int j = 0; j < 8; ++j) o[j] = tile[g2 * 8 + j][n];
      *(us8*)(out + (size_t)n * TP + kc) = o;
    }
  }
}

// ============ fused QK^T -> head-softmax -> PV  ============
// Block = (b, q-tile of 32) x all 12 heads x all 64 d. 4 waves; wave w owns
// heads 3w..3w+2. Loop k-tiles of 32:
//   QK^T: Q-frags (regs, loaded once) x K-frags (global, L2-hot) ->
//         dp written to LDS dpx[q*421 + k*13 + h] (pad-swizzled, bank-spread)
//   softmax over h: each thread 4 (q,k) pairs, 12 values each; exp2, rcp;
//         P (bf16) deposited in LDS plds[h][nt][lane][j] == exact B-frag
//         layout for PV (16B aligned per lane, conflict-free)
//   PV (swapped): out^T[d][q] += Vt-frag (A, global 16B/lane) x P-frag (B)
// No dp/P global intermediates. Writes wa into the Q-slot rows it owns.
__global__ __launch_bounds__(256, 2) void fattn(
    const u16* __restrict__ qkvbf, const u16* __restrict__ Vt,
    u16* __restrict__ outbf) {
  __shared__ float dpx[32 * 421 + 16];
  __shared__ __align__(16) u16 plds[NH][2][64][8];

  int b = blockIdx.y;
  int q0 = blockIdx.x * 32;
  int tid = threadIdx.x;
  int w = tid >> 6, l = tid & 63;
  int lm = l & 15, lq = l >> 4;
  const u16* qbase = qkvbf + (size_t)b * T_ * H3;

  // Q fragments, persistent: [hh][qt][ds]
  bf8 qf[3][2][2];
  #pragma unroll
  for (int hh = 0; hh < 3; ++hh) {
    int h = w * 3 + hh;
    #pragma unroll
    for (int qt = 0; qt < 2; ++qt) {
      int row = q0 + qt * 16 + lm; row = row < T_ ? row : T_ - 1;
      #pragma unroll
      for (int ds = 0; ds < 2; ++ds)
        qf[hh][qt][ds] = *(const bf8*)(qbase + (size_t)row * H3 + h * 64 + ds * 32 + lq * 8);
    }
  }

  f4 oacc[3][4][2] = {};   // [hh][mt(d)][nt(q)]

  for (int kt = 0; kt < 19; ++kt) {
    int k0 = kt * 32;

    // ---- QK^T per head ----
    #pragma unroll
    for (int hh = 0; hh < 3; ++hh) {
      int h = w * 3 + hh;
      bf8 kf[2][2];
      #pragma unroll
      for (int nt = 0; nt < 2; ++nt) {
        int krow = k0 + nt * 16 + lm; krow = krow < T_ ? krow : T_ - 1;
        #pragma unroll
        for (int ds = 0; ds < 2; ++ds)
          kf[nt][ds] = *(const bf8*)(qbase + (size_t)krow * H3 + D_ + h * 64 + ds * 32 + lq * 8);
      }
      f4 s[2][2] = {};
      #pragma unroll
      for (int qt = 0; qt < 2; ++qt)
        #pragma unroll
        for (int nt = 0; nt < 2; ++nt) {
          s[qt][nt] = __builtin_amdgcn_mfma_f32_16x16x32_bf16(qf[hh][qt][0], kf[nt][0], s[qt][nt], 0, 0, 0);
          s[qt][nt] = __builtin_amdgcn_mfma_f32_16x16x32_bf16(qf[hh][qt][1], kf[nt][1], s[qt][nt], 0, 0, 0);
        }
      #pragma unroll
      for (int qt = 0; qt < 2; ++qt)
        #pragma unroll
        for (int nt = 0; nt < 2; ++nt)
          #pragma unroll
          for (int r = 0; r < 4; ++r) {
            int q = qt * 16 + lq * 4 + r;
            int k = nt * 16 + lm;
            dpx[q * 421 + k * 13 + h] = s[qt][nt][r];
          }
    }
    __syncthreads();

    // ---- softmax over 12 heads per (q,k) ----
    #pragma unroll
    for (int p = 0; p < 4; ++p) {
      int flat = p * 256 + tid;
      int q = flat >> 5, k = flat & 31;
      const float* dv = &dpx[q * 421 + k * 13];
      float v[NH];
      #pragma unroll
      for (int h = 0; h < NH; ++h) v[h] = dv[h];
      float m = v[0];
      #pragma unroll
      for (int h = 1; h < NH; ++h) m = fmaxf(m, v[h]);
      float sum = 0.f;
      #pragma unroll
      for (int h = 0; h < NH; ++h) { v[h] = exp2f((v[h] - m) * SM_SCALE); sum += v[h]; }
      float inv = __builtin_amdgcn_rcpf(sum);
      int valid = (k0 + k) < T_;
      #pragma unroll
      for (int h = 0; h < NH; ++h) {
        u16 pb = valid ? f2bf(v[h] * inv) : (u16)0;
        plds[h][q >> 4][(q & 15) + 16 * (k >> 3)][k & 7] = pb;
      }
    }
    __syncthreads();

    // ---- PV (swapped: out^T = Vt-frag x P^T-frag) ----
    #pragma unroll
    for (int hh = 0; hh < 3; ++hh) {
      int h = w * 3 + hh;
      const u16* vb = Vt + (size_t)(b * NH + h) * 128 * TP;
      bf8 vf[4], pf[2];
      #pragma unroll
      for (int mt = 0; mt < 4; ++mt)
        vf[mt] = *(const bf8*)(vb + (size_t)(mt * 16 + lm) * TP + k0 + lq * 8);
      #pragma unroll
      for (int nt = 0; nt < 2; ++nt)
        pf[nt] = *(const bf8*)&plds[h][nt][l][0];
      #pragma unroll
      for (int mt = 0; mt < 4; ++mt)
        #pragma unroll
        for (int nt = 0; nt < 2; ++nt)
          oacc[hh][mt][nt] = __builtin_amdgcn_mfma_f32_16x16x32_bf16(
              vf[mt], pf[nt], oacc[hh][mt][nt], 0, 0, 0);
    }
    // no barrier needed: next dpx write is after the QK^T-end barrier;
    // next plds write is after it too; PV reads drained by that barrier.
  }

  // ---- epilogue: out^T C-layout col=q, row=d ----
  u16* ob = outbf + (size_t)b * T_ * H3;
  #pragma unroll
  for (int hh = 0; hh < 3; ++hh) {
    int h = w * 3 + hh;
    #pragma unroll
    for (int nt = 0; nt < 2; ++nt) {
      int q = q0 + nt * 16 + lm;
      if (q >= T_) continue;
      #pragma unroll
      for (int mt = 0; mt < 4; ++mt)
        #pragma unroll
        for (int r = 0; r < 4; ++r) {
          int d = mt * 16 + lq * 4 + r;
          ob[(size_t)q * H3 + h * 64 + d] = f2bf(oacc[hh][mt][nt][r]);
        }
    }
  }
}

// ============ 128x128 BK=32 double-buffered pipelined GEMM ============
// 4 waves (2x2), per-wave 64x64; LDS 32 KiB -> 4 blocks/CU. Granule
// XOR-swizzle (slot s of row r holds granule s^((r>>1)&3)); inverse-swizzled
// global source (rule #21). Counted vmcnt(4). 2 barriers / K-tile.
// EPI: 0 = bias -> bf16   1 = bias+res -> f32   2 = bias+gelu -> bf16
template <int EPI>
__global__ __launch_bounds__(256, 4) void gemm128(
    const u16* __restrict__ A, int lda,
    const u16* __restrict__ Bt, int ldb,
    const float* __restrict__ bias,
    const float* __restrict__ res, int ldr,
    float* __restrict__ Cf, u16* __restrict__ Cb, int ldc,
    int M, int K) {
  __shared__ u16 lds[16384];           // A: [2][4096] @0, B: [2][4096] @8192
  const int NKT = K >> 5;

  // bijective XCD swizzle (m204)
  int gx = gridDim.x;
  int nwg = gx * (int)gridDim.y;
  int orig = blockIdx.y * gx + blockIdx.x;
  int qq = nwg >> 3, rr = nwg & 7;
  int xcd = orig & 7, loc = orig >> 3;
  int wg = (xcd < rr ? xcd * (qq + 1) : rr * (qq + 1) + (xcd - rr) * qq) + loc;
  int by = wg / gx, bx = wg - by * gx;
  int m_base = by * 128, n_base = bx * 128;

  int tid = threadIdx.x;
  int wid = tid >> 6, lane = tid & 63;
  int wr = wid >> 1, wc = wid & 1;
  int lm = lane & 15, q = lane >> 4;

  int r0 = tid >> 2, g0 = (tid & 3) ^ ((r0 >> 1) & 3);
  int M1 = M - 1;
  int ra0 = m_base + r0;       ra0 = ra0 < M1 ? ra0 : M1;
  int ra1 = m_base + 64 + r0;  ra1 = ra1 < M1 ? ra1 : M1;
  const u16* pa0 = A + (size_t)ra0 * lda + g0 * 8;
  const u16* pa1 = A + (size_t)ra1 * lda + g0 * 8;
  const u16* pb0 = Bt + (size_t)(n_base + r0)      * ldb + g0 * 8;
  const u16* pb1 = Bt + (size_t)(n_base + 64 + r0) * ldb + g0 * 8;

  auto STAGE = [&](int p, int t) {
    size_t ko = (size_t)t * 32;
    int Ab = p * 4096, Bb = 8192 + p * 4096;
    GLOAD_LDS16(pa0 + ko, lds + Ab + tid * 8);
    GLOAD_LDS16(pa1 + ko, lds + Ab + 2048 + tid * 8);
    GLOAD_LDS16(pb0 + ko, lds + Bb + tid * 8);
    GLOAD_LDS16(pb1 + ko, lds + Bb + 2048 + tid * 8);
  };

  int ge0 = (q ^ ((lm >> 1) & 3)) * 8;
  int aoffb = (wr * 64 + lm) * 32;
  int boffb = 8192 + (wc * 64 + lm) * 32;

  f4 acc[4][4] = {};

  STAGE(0, 0);

  for (int t = 0; t < NKT; ++t) {
    int p = t & 1;
    int tN = t + 1 < NKT ? t + 1 : t;

    STAGE(p ^ 1, tN);
    asm volatile("s_waitcnt vmcnt(4)" ::: "memory");
    __builtin_amdgcn_s_barrier();
    __builtin_amdgcn_sched_barrier(0);

    bf8 af[4], bfr[4];
    #pragma unroll
    for (int mt = 0; mt < 4; ++mt)
      af[mt] = *(const bf8*)(lds + p * 4096 + aoffb + mt * 512 + ge0);
    #pragma unroll
    for (int nt = 0; nt < 4; ++nt)
      bfr[nt] = *(const bf8*)(lds + p * 4096 + boffb + nt * 512 + ge0);
    asm volatile("s_waitcnt lgkmcnt(0)" ::: "memory");
    __builtin_amdgcn_sched_barrier(0);

    __builtin_amdgcn_s_setprio(1);
    #pragma unroll
    for (int mt = 0; mt < 4; ++mt)
      #pragma unroll
      for (int nt = 0; nt < 4; ++nt)
        acc[mt][nt] = __builtin_amdgcn_mfma_f32_16x16x32_bf16(
            af[mt], bfr[nt], acc[mt][nt], 0, 0, 0);
    __builtin_amdgcn_s_setprio(0);

    __builtin_amdgcn_s_barrier();
    __builtin_amdgcn_sched_barrier(0);
  }

  asm volatile("s_waitcnt vmcnt(0)" ::: "memory");

  #pragma unroll
  for (int mt = 0; mt < 4; ++mt) {
    #pragma unroll
    for (int i = 0; i < 4; ++i) {
      int grow = m_base + wr * 64 + mt * 16 + q * 4 + i;
      if (grow >= M) continue;
      #pragma unroll
      for (int nt = 0; nt < 4; ++nt) {
        int gcol = n_base + wc * 64 + nt * 16 + lm;
        float v = acc[mt][nt][i];
        if (EPI == 0) {
          v += bias[gcol];
          Cb[(size_t)grow * ldc + gcol] = f2bf(v);
        } else if (EPI == 1) {
          v += bias[gcol] + res[(size_t)grow * ldr + gcol];
          Cf[(size_t)grow * ldc + gcol] = v;
        } else {
          v += bias[gcol];
          Cb[(size_t)grow * ldc + gcol] = f2bf(gelu_fast(v));
        }
      }
    }
  }
}

// ---------------- launch ----------------
extern "C" void kernel_launch(void* const* d_in, const int* in_sizes, int n_in,
                              void* d_out, int out_size, void* d_ws, size_t ws_size,
                              hipStream_t stream) {
  const float* x     = (const float*)d_in[0];
  const float* ln1w  = (const float*)d_in[1];
  const float* ln1b  = (const float*)d_in[2];
  const float* qkvw  = (const float*)d_in[3];
  const float* qkvb  = (const float*)d_in[4];
  const float* projw = (const float*)d_in[5];
  const float* projb = (const float*)d_in[6];
  const float* ln2w  = (const float*)d_in[7];
  const float* ln2b  = (const float*)d_in[8];
  const float* fc1w  = (const float*)d_in[9];
  const float* fc1b  = (const float*)d_in[10];
  const float* fc2w  = (const float*)d_in[11];
  const float* fc2b  = (const float*)d_in[12];
  float* out = (float*)d_out;

  // ---- workspace layout ----
  u16* qkvwT  = (u16*)d_ws;                       // [2304][768]
  u16* projwT = qkvwT  + (size_t)H3 * D_;         // [768][768]
  u16* fc1wT  = projwT + (size_t)D_ * D_;         // [3072][768]
  u16* fc2wT  = fc1wT  + (size_t)HD * D_;         // [768][3072]
  char* chunk = (char*)(fc2wT + (size_t)D_ * HD);
  const size_t wbytes = ((size_t)H3 * D_ + (size_t)D_ * D_ + 2 * (size_t)HD * D_) * 2;
  size_t avail = ws_size - wbytes;

  const size_t per_batch =
      (size_t)T_ * D_ * 2 + (size_t)T_ * H3 * 2 + (size_t)NH * 128 * TP * 2;
  int NB = (int)(avail / per_batch);
  if (NB < 1)  NB = 1;
  if (NB > B_) NB = B_;

  u16* ybf   = (u16*)chunk;
  u16* qkvbf = ybf + (size_t)NB * T_ * D_;
  u16* Vt    = qkvbf + (size_t)NB * T_ * H3;

  // ---- weights: fp32 [K,N] -> bf16 [N,K] ----
  wconv<<<dim3(H3 / 64, D_ / 64), 256, 0, stream>>>(qkvw, qkvwT, D_, H3);
  wconv<<<dim3(D_ / 64, D_ / 64), 256, 0, stream>>>(projw, projwT, D_, D_);
  wconv<<<dim3(HD / 64, D_ / 64), 256, 0, stream>>>(fc1w, fc1wT, D_, HD);
  wconv<<<dim3(D_ / 64, HD / 64), 256, 0, stream>>>(fc2w, fc2wT, HD, D_);

  // ---- attention branch, chunked over batches ----
  for (int b0 = 0; b0 < B_; b0 += NB) {
    int nb = (B_ - b0 < NB) ? (B_ - b0) : NB;
    int rows = nb * T_;
    int mb = (rows + 127) / 128;
    const float* xc = x + (size_t)b0 * T_ * D_;
    float* outc = out + (size_t)b0 * T_ * D_;

    ln_bf16<<<rows, 256, 0, stream>>>(xc, ln1w, ln1b, ybf);
    gemm128<0><<<dim3(H3 / 128, mb), 256, 0, stream>>>(
        ybf, D_, qkvwT, D_, qkvb, nullptr, 0, nullptr, qkvbf, H3,
        rows, D_);
    vt_prep<<<dim3(10, 1, nb * NH), 256, 0, stream>>>(qkvbf, Vt);
    fattn<<<dim3(19, nb), 256, 0, stream>>>(qkvbf, Vt, qkvbf);
    gemm128<1><<<dim3(D_ / 128, mb), 256, 0, stream>>>(
        qkvbf, H3, projwT, D_, projb, xc, D_, outc, nullptr, D_,
        rows, D_);
  }

  // ---- MLP branch, chunked over rows ----
  size_t chrows = avail / ((size_t)D_ * 2 + (size_t)HD * 2);
  int CH = (chrows > (size_t)BT) ? BT : (int)chrows;
  CH &= ~127;
  if (CH < 128) CH = 128;
  for (int r0 = 0; r0 < BT; r0 += CH) {
    int rows = (BT - r0 < CH) ? (BT - r0) : CH;
    int mb = (rows + 127) / 128;
    float* oc = out + (size_t)r0 * D_;
    u16* y2  = (u16*)chunk;
    u16* hdn = y2 + (size_t)CH * D_;

    ln_bf16<<<rows, 256, 0, stream>>>(oc, ln2w, ln2b, y2);
    gemm128<2><<<dim3(HD / 128, mb), 256, 0, stream>>>(
        y2, D_, fc1wT, D_, fc1b, nullptr, 0, nullptr, hdn, HD,
        rows, D_);
    gemm128<1><<<dim3(D_ / 128, mb), 256, 0, stream>>>(
        hdn, HD, fc2wT, HD, fc2b, oc, D_, oc, nullptr, D_,
        rows, HD);
  }
}